// Round 11
// baseline (258.856 us; speedup 1.0000x reference)
//
#include <hip/hip_runtime.h>
#include <stdint.h>

// C=32 captions, I=32 images, T=40 words, R=36 regions, D=1024.
// R22: attack gates2's serial chain (96us invariant across R20/R21 despite
// removing barriers+staging => latency-bound per-wave chain, 10 waves/CU
// resident). Changes:
//   - d-SPLIT x2: block owns 4 chunks (half of d); grid 1280->2560
//     (10 blocks/CU -> 32 waves/CU cap). Halves write disjoint S2a/S2b
//     partials; score_k<1> sums them (2 extra loads, no atomics).
//   - imgF fragment pre-pack: S2's A-operand (imgb, 2KB-stride 16-segment
//     scatter, 6/chunk) -> packed [i][mt][w][lane][8] built in prep from
//     fp32 img. ALL gates2 global accesses now wave-contiguous.
// Math byte-identical to R20/R21 (passed).

typedef unsigned short u16;
typedef __attribute__((ext_vector_type(8))) short bf16x8;
typedef __attribute__((ext_vector_type(4))) float f32x4;

#define MFMA_BF16(a, b, c) __builtin_amdgcn_mfma_f32_16x16x32_bf16((a), (b), (c), 0, 0, 0)

__device__ __forceinline__ float bf2f(u16 u) {
  union { unsigned v; float f; } x; x.v = ((unsigned)u) << 16; return x.f;
}
__device__ __forceinline__ u16 f2bf(float f) {  // round-to-nearest-even
  union { float f; unsigned v; } x; x.f = f;
  return (u16)((x.v + 0x7fffu + ((x.v >> 16) & 1u)) >> 16);
}
__device__ __forceinline__ float frcp(float x) { return __builtin_amdgcn_rcpf(x); }
// async 16B global->LDS (DMA; LDS dest = wave-uniform base + lane*16)
__device__ __forceinline__ void gl2lds16(const u16* g, u16* l) {
  __builtin_amdgcn_global_load_lds((const __attribute__((address_space(1))) void*)g,
                                   (__attribute__((address_space(3))) void*)l, 16, 0, 0);
}

// fragment index for pre/cap: element (ct, d) -> u16 index in preP layout.
// gates2 thread (wv,quad,l15) at (dc,mt,nt) reads lane=quad*16+l15:
//   ct = ct0 + nt*16 + l15,  d = dc*128 + wv*32 + mt*16 + quad*4 + rg
__device__ __forceinline__ size_t fragIdx(int ct, int d) {
  const int tile = ct >> 5, nt = (ct >> 4) & 1, l15 = ct & 15;
  const int dc = d >> 7, wvd = (d >> 5) & 3, mt = (d >> 4) & 1;
  const int quad = (d >> 2) & 3, rg = d & 3;
  const int lane = quad * 16 + l15;
  return ((((((size_t)tile * 8 + dc) * 4 + wvd) * 2 + mt) * 2 + nt) * 64 + lane) * 4 + rg;
}

// ---------------------------------------------------------------------------
// prep: [0,1152) img cvt; [1152,2432) cap cvt (+capP frag); [2432,6528) W
// transpose; [6528,6848) capnorm; [6848,8896) zero cwF pads; [8896,9664)
// imgF fragment pack (reads fp32 img directly - no intra-launch dep).
__global__ void prep_k(const float* __restrict__ img, const float* __restrict__ cap,
                       const float* __restrict__ Wl, const float* __restrict__ Wg,
                       u16* __restrict__ imgb, u16* __restrict__ capb,
                       u16* __restrict__ capP, u16* __restrict__ imgF,
                       u16* __restrict__ WTl, u16* __restrict__ WTg,
                       float* __restrict__ cnorm, u16* __restrict__ cwF0) {
  __shared__ u16 tile[32][33];
  const int b = blockIdx.x, tid = threadIdx.x;
  if (b < 1152) {
    const int idx = (b * 256 + tid) * 4;
    const float4 v = *(const float4*)(img + idx);
    u16 o[4] = {f2bf(v.x), f2bf(v.y), f2bf(v.z), f2bf(v.w)};
    *(uint2*)(imgb + idx) = *(const uint2*)o;
  } else if (b < 2432) {
    const int idx = ((b - 1152) * 256 + tid) * 4;
    const float4 v = *(const float4*)(cap + idx);
    u16 o[4] = {f2bf(v.x), f2bf(v.y), f2bf(v.z), f2bf(v.w)};
    *(uint2*)(capb + idx) = *(const uint2*)o;
    const int ct = idx >> 10, d0 = idx & 1023;
    *(uint2*)(capP + fragIdx(ct, d0)) = *(const uint2*)o;  // rg=0: 8B aligned
  } else if (b < 6528) {
    const int b2 = b - 2432;
    const int bx = b2 & 63, by = (b2 >> 6) & 31, bz = b2 >> 11;
    const float* src = bz ? Wg : Wl;
    u16* dst = bz ? WTg : WTl;
    const int k0 = bx * 32, n0 = by * 32;
    const int tx = tid & 31, ty = tid >> 5;
#pragma unroll
    for (int j = 0; j < 4; ++j)
      tile[ty + 8 * j][tx] = f2bf(src[(size_t)(k0 + ty + 8 * j) * 1024 + n0 + tx]);
    __syncthreads();
#pragma unroll
    for (int j = 0; j < 4; ++j)
      dst[(size_t)(n0 + ty + 8 * j) * 2048 + k0 + tx] = tile[tx][ty + 8 * j];
  } else if (b < 6848) {
    const int wv = tid >> 6, lane = tid & 63;
    const int row = (b - 6528) * 4 + wv;  // < 1280
    const float* p = cap + ((size_t)row << 10) + lane * 16;
    float s = 0.f;
#pragma unroll
    for (int e = 0; e < 16; ++e) { float v = p[e]; s += v * v; }
#pragma unroll
    for (int off = 32; off > 0; off >>= 1) s += __shfl_down(s, off, 64);
    if (lane == 0) cnorm[row] = sqrtf(s);
  } else if (b < 8896) {
    const int idx = ((b - 6848) * 256 + tid) * 8;
    uint4 z; z.x = z.y = z.z = z.w = 0u;
    *(uint4*)(cwF0 + idx) = z;
  } else {
    // imgF pack: element (i, r, d) -> [i][mt][w][lane][8]
    // (r = mt*16 + (lane&15), d = w*32 + (lane>>4)*8 + e); r>=36 -> 0.
    const int g = (b - 8896) * 256 + tid;  // < 196608
    const int i = g / 6144, rem = g - i * 6144;
    const int mt = rem >> 11, rem2 = rem & 2047;
    const int w = rem2 >> 6, lane = rem2 & 63;
    const int r = mt * 16 + (lane & 15);
    const int d = w * 32 + (lane >> 4) * 8;
    u16 o[8];
    if (r < 36) {
      const float* p = img + (((size_t)(i * 36 + r)) << 10) + d;
      const float4 v0 = *(const float4*)p;
      const float4 v1 = *(const float4*)(p + 4);
      o[0] = f2bf(v0.x); o[1] = f2bf(v0.y); o[2] = f2bf(v0.z); o[3] = f2bf(v0.w);
      o[4] = f2bf(v1.x); o[5] = f2bf(v1.y); o[6] = f2bf(v1.z); o[7] = f2bf(v1.w);
    } else {
#pragma unroll
      for (int e = 0; e < 8; ++e) o[e] = 0;
    }
    *(uint4*)(imgF + (size_t)g * 8) = *(const uint4*)o;
  }
}

// ---------------------------------------------------------------------------
// Merged GEMM launch: [0,640) s1gemm; [640,944) gemmw; [944,976) gram.
// gemmw img part -> cwF fragment layout; cap part -> preP fragment layout.
__global__ __launch_bounds__(256, 2) void gemms_k(
    const u16* __restrict__ capb, const u16* __restrict__ imgb,
    const u16* __restrict__ WTl, const u16* __restrict__ WTg,
    u16* __restrict__ prePL, u16* __restrict__ prePG,
    u16* __restrict__ cwFL, u16* __restrict__ cwFG,
    const float* __restrict__ bL, const float* __restrict__ bG,
    float* __restrict__ S1, u16* __restrict__ Ghi, u16* __restrict__ Glo) {
  __shared__ __align__(16) char lsU[20480];
  const int bid = blockIdx.x;
  const int tid = threadIdx.x;
  const int wv = tid >> 6, lane = tid & 63;
  const int quad = lane >> 4, l15 = lane & 15;
  const bf16x8 zero8 = {0, 0, 0, 0, 0, 0, 0, 0};

  if (bid < 640) {
    // ---- S1 GEMM: out[i][m][r] = sum_d cap[m,d]*ctx_i[r,d]; m-tile 64.
    u16* lsA = (u16*)lsU;
    u16* lsB = (u16*)(lsU + 4096);
    const int i = bid & 31, m0 = (bid >> 5) * 64;
    const u16* B = imgb + (size_t)i * 36 * 1024;
    f32x4 acc[3];
#pragma unroll
    for (int b = 0; b < 3; ++b) acc[b] = (f32x4){0.f, 0.f, 0.f, 0.f};
    for (int kt = 0; kt < 32; ++kt) {
      if (kt) __syncthreads();
      const int rr = tid >> 2, j = tid & 3;
      const int js = j ^ ((rr >> 2) & 3);
      gl2lds16(capb + (size_t)(m0 + rr) * 1024 + kt * 32 + js * 8,
               lsA + (size_t)(wv * 64) * 8);
      const int rc = rr < 36 ? rr : 35;
      gl2lds16(B + (size_t)rc * 1024 + kt * 32 + js * 8,
               lsB + (size_t)(wv * 64) * 8);
      __syncthreads();
      const int ra = wv * 16 + l15;
      const bf16x8 a2 = *(const bf16x8*)(lsA + ra * 32 + (quad ^ ((ra >> 2) & 3)) * 8);
      bf16x8 b3[3];
#pragma unroll
      for (int nf = 0; nf < 3; ++nf) {
        const int rb = nf * 16 + l15;
        const bf16x8 bv = *(const bf16x8*)(lsB + rb * 32 + (quad ^ ((rb >> 2) & 3)) * 8);
        b3[nf] = (rb < 36) ? bv : zero8;
      }
#pragma unroll
      for (int nf = 0; nf < 3; ++nf) acc[nf] = MFMA_BF16(a2, b3[nf], acc[nf]);
    }
#pragma unroll
    for (int nf = 0; nf < 3; ++nf)
#pragma unroll
      for (int rg = 0; rg < 4; ++rg) {
        const int m = m0 + wv * 16 + quad * 4 + rg;
        S1[((size_t)i * 1280 + m) * 48 + nf * 16 + l15] = acc[nf][rg];
      }
  } else if (bid < 944) {
    // ---- dual-B GEMM over A = [capb(1280); imgb(1152)], K=1024.
    u16* lsA = (u16*)lsU;
    u16* lsBl = (u16*)(lsU + 4096);
    u16* lsBg = (u16*)(lsU + 12288);
    const int b2 = bid - 640;
    const int bm = b2 >> 3, bn = b2 & 7;
    const bool iscap = bm < 20;
    const u16* A = iscap ? capb + (size_t)bm * 64 * 1024
                         : imgb + (size_t)(bm - 20) * 64 * 1024;
    const int kofs = iscap ? 0 : 1024;
    const int wm = (wv & 1) * 32, wn = (wv >> 1) * 64;
    f32x4 accL[2][4], accG[2][4];
#pragma unroll
    for (int a = 0; a < 2; ++a)
#pragma unroll
      for (int b = 0; b < 4; ++b) {
        accL[a][b] = (f32x4){0.f, 0.f, 0.f, 0.f};
        accG[a][b] = (f32x4){0.f, 0.f, 0.f, 0.f};
      }
    for (int kt = 0; kt < 32; ++kt) {
      if (kt) __syncthreads();
      {
        const int row = tid >> 2, c8 = tid & 3;
        const int js = c8 ^ (row & 3);
        gl2lds16(A + (size_t)row * 1024 + kt * 32 + js * 8,
                 lsA + (size_t)(wv * 64) * 8);
      }
#pragma unroll
      for (int s = 0; s < 2; ++s) {
        const int idx = s * 256 + tid;
        const int row = idx >> 2, c8 = idx & 3;
        const int js = c8 ^ (row & 3);
        const size_t bro = (size_t)(bn * 128 + row) * 2048 + kofs + kt * 32 + js * 8;
        gl2lds16(WTl + bro, lsBl + (size_t)(s * 256 + wv * 64) * 8);
        gl2lds16(WTg + bro, lsBg + (size_t)(s * 256 + wv * 64) * 8);
      }
      __syncthreads();
      bf16x8 af[2], bl8[4], bg8[4];
#pragma unroll
      for (int mt = 0; mt < 2; ++mt) {
        const int ra = wm + mt * 16 + l15;
        af[mt] = *(const bf16x8*)(lsA + ra * 32 + (quad ^ (ra & 3)) * 8);
      }
#pragma unroll
      for (int nt = 0; nt < 4; ++nt) {
        const int rb = wn + nt * 16 + l15;
        const int off = rb * 32 + (quad ^ (rb & 3)) * 8;
        bl8[nt] = *(const bf16x8*)(lsBl + off);
        bg8[nt] = *(const bf16x8*)(lsBg + off);
      }
#pragma unroll
      for (int mt = 0; mt < 2; ++mt)
#pragma unroll
        for (int nt = 0; nt < 4; ++nt) {
          accL[mt][nt] = MFMA_BF16(af[mt], bl8[nt], accL[mt][nt]);
          accG[mt][nt] = MFMA_BF16(af[mt], bg8[nt], accG[mt][nt]);
        }
    }
#pragma unroll
    for (int mt = 0; mt < 2; ++mt)
#pragma unroll
      for (int nt = 0; nt < 4; ++nt) {
        const int n = bn * 128 + wn + nt * 16 + l15;
        if (iscap) {
          const float blv = bL[n], bgv = bG[n];
#pragma unroll
          for (int r = 0; r < 4; ++r) {
            const int m = bm * 64 + wm + mt * 16 + quad * 4 + r;
            const size_t fi = fragIdx(m, n);
            prePL[fi] = f2bf(accL[mt][nt][r] + blv);
            prePG[fi] = f2bf(accG[mt][nt][r] + bgv);
          }
        } else {
          const int db = n >> 4, l15d = n & 15;
#pragma unroll
          for (int r = 0; r < 4; ++r) {
            const int mi = (bm - 20) * 64 + wm + mt * 16 + quad * 4 + r;
            const int i = (mi * 3641) >> 17;   // floor(mi/36), mi<1152
            const int r36 = mi - i * 36;
            const int ksr = r36 >> 5, qd = (r36 & 31) >> 3, e = r36 & 7;
            const size_t gb =
                ((((size_t)i * 64 + db) * 2 + ksr) * 64 + qd * 16 + l15d) * 8 + e;
            cwFL[gb] = f2bf(accL[mt][nt][r]);
            cwFG[gb] = f2bf(accG[mt][nt][r]);
          }
        }
      }
  } else {
    // ---- per-image Gram: G[i] = ctx_i @ ctx_i^T, [48][64] bf16 hi+lo.
    float* lsS = (float*)lsU;  // 48*52*4 = 9984B
    const int i = bid - 944;
    for (int k = tid; k < 48 * 52; k += 256) lsS[k] = 0.f;
    const u16* arow[3]; bool avalid[3];
#pragma unroll
    for (int mt = 0; mt < 3; ++mt) {
      const int r = mt * 16 + l15;
      avalid[mt] = r < 36;
      arow[mt] = imgb + ((size_t)(i * 36 + (r < 36 ? r : 35)) << 10);
    }
    f32x4 acc[3][3];
#pragma unroll
    for (int a = 0; a < 3; ++a)
#pragma unroll
      for (int b = 0; b < 3; ++b) acc[a][b] = (f32x4){0.f, 0.f, 0.f, 0.f};
    for (int kk = wv * 8; kk < wv * 8 + 8; ++kk) {
      const int ko = kk * 32 + quad * 8;
      bf16x8 af[3];
#pragma unroll
      for (int mt = 0; mt < 3; ++mt)
        af[mt] = avalid[mt] ? *(const bf16x8*)(arow[mt] + ko) : zero8;
#pragma unroll
      for (int mt = 0; mt < 3; ++mt)
#pragma unroll
        for (int nt = 0; nt < 3; ++nt)
          acc[mt][nt] = MFMA_BF16(af[mt], af[nt], acc[mt][nt]);
    }
    __syncthreads();
#pragma unroll
    for (int mt = 0; mt < 3; ++mt)
#pragma unroll
      for (int nt = 0; nt < 3; ++nt)
#pragma unroll
        for (int rg = 0; rg < 4; ++rg)
          atomicAdd(&lsS[(nt * 16 + l15) * 52 + mt * 16 + quad * 4 + rg],
                    acc[mt][nt][rg]);
    __syncthreads();
    if (wv == 0) {
#pragma unroll
      for (int nt = 0; nt < 3; ++nt) {
        const int rp = nt * 16 + l15;
#pragma unroll
        for (int mt = 0; mt < 3; ++mt) {
          const f32x4 g = *(const f32x4*)&lsS[rp * 52 + mt * 16 + quad * 4];
          u16 hv[4], lv[4];
#pragma unroll
          for (int rg = 0; rg < 4; ++rg) {
            hv[rg] = f2bf(g[rg]);
            lv[rg] = f2bf(g[rg] - bf2f(hv[rg]));
          }
          const size_t gb = ((size_t)i * 48 + rp) * 64 + mt * 16 + quad * 4;
          *(uint2*)(Ghi + gb) = *(const uint2*)hv;
          *(uint2*)(Glo + gb) = *(const uint2*)lv;
        }
      }
    }
    for (int k = tid; k < 48 * 16; k += 256) {  // zero cols 48..63
      const size_t gb = ((size_t)i * 48 + (k >> 4)) * 64 + 48 + (k & 15);
      Ghi[gb] = 0; Glo[gb] = 0;
    }
  }
}

// ---------------------------------------------------------------------------
// Fused gate + partial S2, d-split. Block (ctt, i, dh) covers chunks
// [dh*4, dh*4+4). All global accesses wave-contiguous (cwF/imgF 1KB,
// preP/capP 512B). No in-loop barriers. Partial S2 -> S2a or S2b.
__global__ __launch_bounds__(256, 4) void gates2_k(
    const u16* __restrict__ cwFL, const u16* __restrict__ cwFG,
    const u16* __restrict__ P1, const u16* __restrict__ prePL,
    const u16* __restrict__ prePG, const u16* __restrict__ capP,
    const u16* __restrict__ imgF, float* __restrict__ S2a,
    float* __restrict__ S2b) {
  __shared__ __align__(16) float lsS2f[32 * 52];
  const int tid = threadIdx.x;
  const int bid = blockIdx.x;
  const int dh = bid & 1, i = (bid >> 1) & 31, ctt = bid >> 6;
  const int ct0 = ctt * 32;
  const int wv = tid >> 6, lane = tid & 63;
  const int quad = lane >> 4, l15 = lane & 15;

  for (int k = tid; k < 32 * 52; k += 256) lsS2f[k] = 0.f;
  __syncthreads();

  // hoisted P1 B-frags (loop-invariant; r>=36 exact zero from score_k)
  bf16x8 bp[2][2];
#pragma unroll
  for (int nt = 0; nt < 2; ++nt)
#pragma unroll
    for (int ks = 0; ks < 2; ++ks)
      bp[nt][ks] = *(const bf16x8*)(
          P1 + ((size_t)i * 1280 + ct0 + nt * 16 + l15) * 64 + ks * 32 + quad * 8);

  f32x4 acc2[3][2];
#pragma unroll
  for (int a = 0; a < 3; ++a)
#pragma unroll
    for (int b = 0; b < 2; ++b) acc2[a][b] = (f32x4){0.f, 0.f, 0.f, 0.f};

  for (int dc = dh * 4; dc < dh * 4 + 4; ++dc) {
    // ---- gate GEMM: cwF frags in-chunk (1KB contiguous per wave)
    f32x4 accL[2][2], accG[2][2];
#pragma unroll
    for (int a = 0; a < 2; ++a)
#pragma unroll
      for (int b = 0; b < 2; ++b) {
        accL[a][b] = (f32x4){0.f, 0.f, 0.f, 0.f};
        accG[a][b] = (f32x4){0.f, 0.f, 0.f, 0.f};
      }
#pragma unroll
    for (int mt = 0; mt < 2; ++mt)
#pragma unroll
      for (int ks = 0; ks < 2; ++ks) {
        const int db = dc * 8 + wv * 2 + mt;
        const size_t co = ((((size_t)i * 64 + db) * 2 + ks) * 64 + lane) * 8;
        const bf16x8 al = *(const bf16x8*)(cwFL + co);
        const bf16x8 ag = *(const bf16x8*)(cwFG + co);
#pragma unroll
        for (int nt = 0; nt < 2; ++nt) {
          accL[mt][nt] = MFMA_BF16(al, bp[nt][ks], accL[mt][nt]);
          accG[mt][nt] = MFMA_BF16(ag, bp[nt][ks], accG[mt][nt]);
        }
      }

    // ---- gating epilogue: fragment-layout global loads (512B/instr)
    const size_t fb = (((size_t)ctt * 8 + dc) * 4 + wv) * 2;
    uint2 ovv[2][2];
#pragma unroll
    for (int mt = 0; mt < 2; ++mt) {
#pragma unroll
      for (int nt = 0; nt < 2; ++nt) {
        const size_t fo = (((fb + mt) * 2 + nt) * 64 + lane) * 4;
        const uint2 plv = *(const uint2*)(prePL + fo);
        const uint2 pgv = *(const uint2*)(prePG + fo);
        const uint2 cfv = *(const uint2*)(capP + fo);
        const float pl4[4] = {bf2f((u16)(plv.x & 0xffffu)), bf2f((u16)(plv.x >> 16)),
                              bf2f((u16)(plv.y & 0xffffu)), bf2f((u16)(plv.y >> 16))};
        const float pg4[4] = {bf2f((u16)(pgv.x & 0xffffu)), bf2f((u16)(pgv.x >> 16)),
                              bf2f((u16)(pgv.y & 0xffffu)), bf2f((u16)(pgv.y >> 16))};
        const float cf4[4] = {bf2f((u16)(cfv.x & 0xffffu)), bf2f((u16)(cfv.x >> 16)),
                              bf2f((u16)(cfv.y & 0xffffu)), bf2f((u16)(cfv.y >> 16))};
        u16 ov[4];
#pragma unroll
        for (int rg = 0; rg < 4; ++rg) {
          const float aL = accL[mt][nt][rg] + pl4[rg];
          const float aG = accG[mt][nt][rg] + pg4[rg];
          const float g = frcp(1.f + __expf(-aG));
          const float u = 2.f * frcp(1.f + __expf(-2.f * aL)) - 1.f;  // tanh
          ov[rg] = f2bf(cf4[rg] * g + u * (1.f - g));
        }
        ovv[mt][nt] = *(const uint2*)ov;
      }
    }

    // ---- S2 partial: B-frag via quad-permute shuffles; A from imgF pack
#pragma unroll
    for (int nt = 0; nt < 2; ++nt) {
      unsigned w[4];
#pragma unroll
      for (int j2 = 0; j2 < 4; ++j2) {
        const int srcl = ((quad & 1) * 2 + (j2 >> 1)) * 16 + l15;
        const unsigned a0 =
            __shfl((j2 & 1) ? ovv[0][nt].y : ovv[0][nt].x, srcl, 64);
        const unsigned a1 =
            __shfl((j2 & 1) ? ovv[1][nt].y : ovv[1][nt].x, srcl, 64);
        w[j2] = (quad >= 2) ? a1 : a0;
      }
      union { unsigned u[4]; bf16x8 v; } bq;
      bq.u[0] = w[0]; bq.u[1] = w[1]; bq.u[2] = w[2]; bq.u[3] = w[3];
      const int wn = dc * 4 + wv;  // 32-d window index
#pragma unroll
      for (int mt = 0; mt < 3; ++mt) {
        const bf16x8 af = *(const bf16x8*)(
            imgF + ((((size_t)i * 3 + mt) * 32 + wn) * 64 + lane) * 8);
        acc2[mt][nt] = MFMA_BF16(af, bq.v, acc2[mt][nt]);
      }
    }
  }
  // ---- merge wave partials (d-slices), write S2 half-tile
#pragma unroll
  for (int mt = 0; mt < 3; ++mt)
#pragma unroll
    for (int nt = 0; nt < 2; ++nt)
#pragma unroll
      for (int rg = 0; rg < 4; ++rg)
        atomicAdd(&lsS2f[(nt * 16 + l15) * 52 + mt * 16 + quad * 4 + rg],
                  acc2[mt][nt][rg]);
  __syncthreads();
  float* S2h = dh ? S2b : S2a;
  for (int idx = tid; idx < 384; idx += 256) {
    const int ct = idx / 12, rq = idx % 12;
    *(f32x4*)(S2h + ((size_t)i * 1280 + ct0 + ct) * 48 + rq * 4) =
        *(const f32x4*)&lsS2f[ct * 52 + rq * 4];
  }
}

// ---------------------------------------------------------------------------
// Per-pair scoring (4 pairs/block, one per wave). PASS2 sums Ssm+SsmB
// (the two d-half partials of S2). Softmax -> P; pn = sum P*S1;
// pw = P^T G P; sim = mean cosine.
template <int PASS2>
__global__ __launch_bounds__(256, 2) void score_k(
    const float* __restrict__ Ssm, const float* __restrict__ SsmB,
    const float* __restrict__ S1,
    const u16* __restrict__ Ghi, const u16* __restrict__ Glo,
    const float* __restrict__ cnorm, u16* __restrict__ P1,
    float* __restrict__ sim1, float* __restrict__ score) {
  __shared__ __align__(16) u16 lsP[4][48 * 72];
  const int tid = threadIdx.x;
  const int wv = tid >> 6, lane = tid & 63;
  const int quad = lane >> 4, l15 = lane & 15;
  const int pair = blockIdx.x * 4 + wv;
  const int c = pair >> 5, i = pair & 31;
  u16* lsPw = lsP[wv];
  for (int k = lane; k < 1728; k += 64) ((unsigned*)lsPw)[k] = 0u;

  float sS[3][3][4], s1f[3][3][4];
  const float* Sb = Ssm + ((size_t)i * 1280 + c * 40) * 48;
  const float* Sb2 = SsmB + ((size_t)i * 1280 + c * 40) * 48;
  const float* S1b = S1 + ((size_t)i * 1280 + c * 40) * 48;
#pragma unroll
  for (int nt = 0; nt < 3; ++nt) {
    const int t = nt * 16 + l15;
    const int tr = t < 40 ? t : 39;
#pragma unroll
    for (int mt = 0; mt < 3; ++mt) {
      f32x4 v = *(const f32x4*)(Sb + (size_t)tr * 48 + mt * 16 + quad * 4);
      if (PASS2) {
        const f32x4 vb = *(const f32x4*)(Sb2 + (size_t)tr * 48 + mt * 16 + quad * 4);
        v += vb;
      }
      if (t >= 40) v = (f32x4){0.f, 0.f, 0.f, 0.f};  // keep l2norm-over-t exact
#pragma unroll
      for (int rg = 0; rg < 4; ++rg) sS[mt][nt][rg] = v[rg];
      if (PASS2) {
        const f32x4 w = *(const f32x4*)(S1b + (size_t)tr * 48 + mt * 16 + quad * 4);
#pragma unroll
        for (int rg = 0; rg < 4; ++rg) s1f[mt][nt][rg] = w[rg];
      } else {
#pragma unroll
        for (int rg = 0; rg < 4; ++rg) s1f[mt][nt][rg] = v[rg];
      }
    }
  }

  // ---- leaky + l2norm over t, temperature softmax over r (in-register)
  float rn[3][4];
#pragma unroll
  for (int mt = 0; mt < 3; ++mt)
#pragma unroll
    for (int rg = 0; rg < 4; ++rg) {
      float s2 = 0.f;
#pragma unroll
      for (int nt = 0; nt < 3; ++nt) {
        float v = sS[mt][nt][rg]; v = v > 0.f ? v : 0.1f * v; s2 += v * v;
      }
      s2 += __shfl_xor(s2, 1, 64); s2 += __shfl_xor(s2, 2, 64);
      s2 += __shfl_xor(s2, 4, 64); s2 += __shfl_xor(s2, 8, 64);
      rn[mt][rg] = sqrtf(s2) + 1e-8f;
    }
  float mx[3] = {-3.0e38f, -3.0e38f, -3.0e38f};
#pragma unroll
  for (int mt = 0; mt < 3; ++mt)
#pragma unroll
    for (int nt = 0; nt < 3; ++nt)
#pragma unroll
      for (int rg = 0; rg < 4; ++rg) {
        const int r = mt * 16 + quad * 4 + rg;
        float v = sS[mt][nt][rg]; v = v > 0.f ? v : 0.1f * v;
        float zz = 9.f * v / rn[mt][rg];
        zz = (r < 36) ? zz : -3.0e38f;
        sS[mt][nt][rg] = zz;
        mx[nt] = fmaxf(mx[nt], zz);
      }
#pragma unroll
  for (int nt = 0; nt < 3; ++nt) {
    mx[nt] = fmaxf(mx[nt], __shfl_xor(mx[nt], 16, 64));
    mx[nt] = fmaxf(mx[nt], __shfl_xor(mx[nt], 32, 64));
  }
  float ss[3] = {0.f, 0.f, 0.f};
#pragma unroll
  for (int mt = 0; mt < 3; ++mt)
#pragma unroll
    for (int nt = 0; nt < 3; ++nt)
#pragma unroll
      for (int rg = 0; rg < 4; ++rg) {
        const float e = __expf(sS[mt][nt][rg] - mx[nt]);
        sS[mt][nt][rg] = e; ss[nt] += e;
      }
#pragma unroll
  for (int nt = 0; nt < 3; ++nt) {
    ss[nt] += __shfl_xor(ss[nt], 16, 64);
    ss[nt] += __shfl_xor(ss[nt], 32, 64);
    ss[nt] = 1.f / ss[nt];
  }
#pragma unroll
  for (int nt = 0; nt < 3; ++nt) {
    const int t = nt * 16 + l15;
#pragma unroll
    for (int mt = 0; mt < 3; ++mt) {
#pragma unroll
      for (int rg = 0; rg < 4; ++rg) sS[mt][nt][rg] *= ss[nt];
      if (t < 40) {
        u16 pv[4];
#pragma unroll
        for (int rg = 0; rg < 4; ++rg) pv[rg] = f2bf(sS[mt][nt][rg]);
        *(uint2*)(lsPw + t * 72 + mt * 16 + quad * 4) = *(const uint2*)pv;
      }
    }
  }

  // ---- pn = sum_r P * S1raw (per t)
  float pnv[3] = {0.f, 0.f, 0.f};
#pragma unroll
  for (int nt = 0; nt < 3; ++nt)
#pragma unroll
    for (int mt = 0; mt < 3; ++mt)
#pragma unroll
      for (int rg = 0; rg < 4; ++rg) pnv[nt] += sS[mt][nt][rg] * s1f[mt][nt][rg];

  // ---- P1 global write (GEMM operand layout, stride 64, zeros beyond r=36)
  if (!PASS2) {
    for (int idx = lane; idx < 320; idx += 64) {
      const int t = idx >> 3, j = idx & 7;
      *(uint4*)(P1 + ((size_t)i * 1280 + c * 40 + t) * 64 + j * 8) =
          *(const uint4*)(lsPw + t * 72 + j * 8);
    }
  }

  // ---- pw = P^T G P via Gram MFMA
  bf16x8 afA[3][2];
#pragma unroll
  for (int mtT = 0; mtT < 3; ++mtT)
#pragma unroll
    for (int ks = 0; ks < 2; ++ks)
      afA[mtT][ks] =
          *(const bf16x8*)(lsPw + (mtT * 16 + l15) * 72 + ks * 32 + quad * 8);
  f32x4 gp[3][3];
#pragma unroll
  for (int a = 0; a < 3; ++a)
#pragma unroll
    for (int b = 0; b < 3; ++b) gp[a][b] = (f32x4){0.f, 0.f, 0.f, 0.f};
#pragma unroll
  for (int ks = 0; ks < 2; ++ks)
#pragma unroll
    for (int mtG = 0; mtG < 3; ++mtG) {
      const size_t gb = ((size_t)i * 48 + mtG * 16 + l15) * 64 + ks * 32 + quad * 8;
      const bf16x8 gh = *(const bf16x8*)(Ghi + gb);
      const bf16x8 gl = *(const bf16x8*)(Glo + gb);
#pragma unroll
      for (int mtT = 0; mtT < 3; ++mtT) {
        gp[mtG][mtT] = MFMA_BF16(gh, afA[mtT][ks], gp[mtG][mtT]);
        gp[mtG][mtT] = MFMA_BF16(gl, afA[mtT][ks], gp[mtG][mtT]);
      }
    }
  float pwv[3] = {0.f, 0.f, 0.f};
#pragma unroll
  for (int nt = 0; nt < 3; ++nt)
#pragma unroll
    for (int mt = 0; mt < 3; ++mt)
#pragma unroll
      for (int rg = 0; rg < 4; ++rg)
        pwv[nt] += sS[mt][nt][rg] * gp[mt][nt][rg];
#pragma unroll
  for (int nt = 0; nt < 3; ++nt) {
    pnv[nt] += __shfl_xor(pnv[nt], 16, 64); pnv[nt] += __shfl_xor(pnv[nt], 32, 64);
    pwv[nt] += __shfl_xor(pwv[nt], 16, 64); pwv[nt] += __shfl_xor(pwv[nt], 32, 64);
  }
  float tot = 0.f;
#pragma unroll
  for (int nt = 0; nt < 3; ++nt) {
    const int t = nt * 16 + l15;
    if (t < 40) {
      const float w2 = sqrtf(fmaxf(pwv[nt], 0.f));
      tot += pnv[nt] / fmaxf(cnorm[c * 40 + t] * w2, 1e-8f);
    }
  }
  tot += __shfl_xor(tot, 1, 64); tot += __shfl_xor(tot, 2, 64);
  tot += __shfl_xor(tot, 4, 64); tot += __shfl_xor(tot, 8, 64);
  if (lane == 0) {
    const float s = tot * (1.f / 40.f);
    if (PASS2) score[i * 32 + c] = sim1[pair] + s;
    else sim1[pair] = s;
  }
}

// ---------------------------------------------------------------------------
extern "C" void kernel_launch(void* const* d_in, const int* in_sizes, int n_in,
                              void* d_out, int out_size, void* d_ws, size_t ws_size,
                              hipStream_t stream) {
  const float* img = (const float*)d_in[0];   // [32][36][1024] fp32
  const float* cap = (const float*)d_in[1];   // [32][40][1024] fp32
  const float* Wl  = (const float*)d_in[2];   // [2048][1024] fp32
  const float* bl  = (const float*)d_in[3];   // [1024] fp32
  const float* Wg  = (const float*)d_in[4];
  const float* bg  = (const float*)d_in[5];
  float* out = (float*)d_out;                 // [32][32] fp32

  char* ws = (char*)d_ws;
  float* cnrm = (float*)ws;               ws += 5120;
  float* sim1 = (float*)ws;               ws += 4096;
  u16*   WTl  = (u16*)ws;                 ws += (size_t)1024 * 2048 * 2;   // 4.2 MB
  u16*   WTg  = (u16*)ws;                 ws += (size_t)1024 * 2048 * 2;   // 4.2 MB
  u16*   prePL= (u16*)ws;                 ws += (size_t)1280 * 1024 * 2;   // 2.6 MB
  u16*   prePG= (u16*)ws;                 ws += (size_t)1280 * 1024 * 2;   // 2.6 MB
  u16*   capb = (u16*)ws;                 ws += (size_t)1280 * 1024 * 2;   // 2.6 MB
  u16*   capP = (u16*)ws;                 ws += (size_t)1280 * 1024 * 2;   // 2.6 MB
  u16*   imgb = (u16*)ws;                 ws += (size_t)1152 * 1024 * 2;   // 2.4 MB
  u16*   imgF = (u16*)ws;                 ws += (size_t)32 * 3 * 32 * 64 * 8 * 2;  // 3.1 MB
  u16*   Ghi  = (u16*)ws;                 ws += (size_t)32 * 48 * 64 * 2;  // 196 KB
  u16*   Glo  = (u16*)ws;                 ws += (size_t)32 * 48 * 64 * 2;  // 196 KB
  u16*   cwFL = (u16*)ws;                 ws += (size_t)32 * 64 * 2 * 64 * 8 * 2;  // 4.2 MB
  u16*   cwFG = (u16*)ws;                 ws += (size_t)32 * 64 * 2 * 64 * 8 * 2;  // 4.2 MB
  float* S1   = (float*)ws;               ws += (size_t)32 * 1280 * 48 * 4;  // 7.9 MB
  float* S2a  = (float*)ws;               ws += (size_t)32 * 1280 * 48 * 4;  // 7.9 MB
  float* S2b  = (float*)ws;               ws += (size_t)32 * 1280 * 48 * 4;  // 7.9 MB
  u16*   P1   = (u16*)ws;                 ws += (size_t)32 * 1280 * 64 * 2;  // 5.2 MB

  prep_k<<<9664, 256, 0, stream>>>(img, cap, Wl, Wg, imgb, capb, capP, imgF,
                                   WTl, WTg, cnrm, cwFL);
  gemms_k<<<976, 256, 0, stream>>>(capb, imgb, WTl, WTg, prePL, prePG,
                                   cwFL, cwFG, bl, bg, S1, Ghi, Glo);
  score_k<0><<<256, 256, 0, stream>>>(S1, S1, S1, Ghi, Glo, cnrm, P1, sim1, out);
  gates2_k<<<2560, 256, 0, stream>>>(cwFL, cwFG, P1, prePL, prePG, capP,
                                     imgF, S2a, S2b);
  score_k<1><<<256, 256, 0, stream>>>(S2a, S2b, S1, Ghi, Glo, cnrm, P1, sim1, out);
}

// Round 12
// 231.425 us; speedup vs baseline: 1.1185x; 1.1185x over previous
//
#include <hip/hip_runtime.h>
#include <stdint.h>

// C=32 captions, I=32 images, T=40 words, R=36 regions, D=1024.
// R23: recombine proven parts. R22's d-split was the regression (+24us:
// doubled per-block fixed cost, no overlap gain); its imgF pack was the
// win (FETCH 42.8->29.9MB, verified correct). This round = EXACT R21
// gates2 (96us, grid 1280, 8 chunks, no in-loop barriers) with only the
// S2 A-operand switched imgb->imgF (wave-contiguous 1KB loads; removes
// the last 16-segment scatter, 6 loads/chunk). prep gains the imgF pack
// section. Everything else byte-identical to R21 (passed).

typedef unsigned short u16;
typedef __attribute__((ext_vector_type(8))) short bf16x8;
typedef __attribute__((ext_vector_type(4))) float f32x4;

#define MFMA_BF16(a, b, c) __builtin_amdgcn_mfma_f32_16x16x32_bf16((a), (b), (c), 0, 0, 0)

__device__ __forceinline__ float bf2f(u16 u) {
  union { unsigned v; float f; } x; x.v = ((unsigned)u) << 16; return x.f;
}
__device__ __forceinline__ u16 f2bf(float f) {  // round-to-nearest-even
  union { float f; unsigned v; } x; x.f = f;
  return (u16)((x.v + 0x7fffu + ((x.v >> 16) & 1u)) >> 16);
}
__device__ __forceinline__ float frcp(float x) { return __builtin_amdgcn_rcpf(x); }
// async 16B global->LDS (DMA; LDS dest = wave-uniform base + lane*16)
__device__ __forceinline__ void gl2lds16(const u16* g, u16* l) {
  __builtin_amdgcn_global_load_lds((const __attribute__((address_space(1))) void*)g,
                                   (__attribute__((address_space(3))) void*)l, 16, 0, 0);
}

// fragment index for pre/cap: element (ct, d) -> u16 index in preP layout.
// gates2 thread (wv,quad,l15) at (dc,mt,nt) reads lane=quad*16+l15:
//   ct = ct0 + nt*16 + l15,  d = dc*128 + wv*32 + mt*16 + quad*4 + rg
__device__ __forceinline__ size_t fragIdx(int ct, int d) {
  const int tile = ct >> 5, nt = (ct >> 4) & 1, l15 = ct & 15;
  const int dc = d >> 7, wvd = (d >> 5) & 3, mt = (d >> 4) & 1;
  const int quad = (d >> 2) & 3, rg = d & 3;
  const int lane = quad * 16 + l15;
  return ((((((size_t)tile * 8 + dc) * 4 + wvd) * 2 + mt) * 2 + nt) * 64 + lane) * 4 + rg;
}

// ---------------------------------------------------------------------------
// prep: [0,1152) img cvt; [1152,2432) cap cvt (+capP frag); [2432,6528) W
// transpose; [6528,6848) capnorm; [6848,8896) zero cwF pads; [8896,9664)
// imgF fragment pack (reads fp32 img directly - no intra-launch dep).
__global__ void prep_k(const float* __restrict__ img, const float* __restrict__ cap,
                       const float* __restrict__ Wl, const float* __restrict__ Wg,
                       u16* __restrict__ imgb, u16* __restrict__ capb,
                       u16* __restrict__ capP, u16* __restrict__ imgF,
                       u16* __restrict__ WTl, u16* __restrict__ WTg,
                       float* __restrict__ cnorm, u16* __restrict__ cwF0) {
  __shared__ u16 tile[32][33];
  const int b = blockIdx.x, tid = threadIdx.x;
  if (b < 1152) {
    const int idx = (b * 256 + tid) * 4;
    const float4 v = *(const float4*)(img + idx);
    u16 o[4] = {f2bf(v.x), f2bf(v.y), f2bf(v.z), f2bf(v.w)};
    *(uint2*)(imgb + idx) = *(const uint2*)o;
  } else if (b < 2432) {
    const int idx = ((b - 1152) * 256 + tid) * 4;
    const float4 v = *(const float4*)(cap + idx);
    u16 o[4] = {f2bf(v.x), f2bf(v.y), f2bf(v.z), f2bf(v.w)};
    *(uint2*)(capb + idx) = *(const uint2*)o;
    const int ct = idx >> 10, d0 = idx & 1023;
    *(uint2*)(capP + fragIdx(ct, d0)) = *(const uint2*)o;  // rg=0: 8B aligned
  } else if (b < 6528) {
    const int b2 = b - 2432;
    const int bx = b2 & 63, by = (b2 >> 6) & 31, bz = b2 >> 11;
    const float* src = bz ? Wg : Wl;
    u16* dst = bz ? WTg : WTl;
    const int k0 = bx * 32, n0 = by * 32;
    const int tx = tid & 31, ty = tid >> 5;
#pragma unroll
    for (int j = 0; j < 4; ++j)
      tile[ty + 8 * j][tx] = f2bf(src[(size_t)(k0 + ty + 8 * j) * 1024 + n0 + tx]);
    __syncthreads();
#pragma unroll
    for (int j = 0; j < 4; ++j)
      dst[(size_t)(n0 + ty + 8 * j) * 2048 + k0 + tx] = tile[tx][ty + 8 * j];
  } else if (b < 6848) {
    const int wv = tid >> 6, lane = tid & 63;
    const int row = (b - 6528) * 4 + wv;  // < 1280
    const float* p = cap + ((size_t)row << 10) + lane * 16;
    float s = 0.f;
#pragma unroll
    for (int e = 0; e < 16; ++e) { float v = p[e]; s += v * v; }
#pragma unroll
    for (int off = 32; off > 0; off >>= 1) s += __shfl_down(s, off, 64);
    if (lane == 0) cnorm[row] = sqrtf(s);
  } else if (b < 8896) {
    const int idx = ((b - 6848) * 256 + tid) * 8;
    uint4 z; z.x = z.y = z.z = z.w = 0u;
    *(uint4*)(cwF0 + idx) = z;
  } else {
    // imgF pack: element (i, r, d) -> [i][mt][w][lane][8]
    // (r = mt*16 + (lane&15), d = w*32 + (lane>>4)*8 + e); r>=36 -> 0.
    const int g = (b - 8896) * 256 + tid;  // < 196608
    const int i = g / 6144, rem = g - i * 6144;
    const int mt = rem >> 11, rem2 = rem & 2047;
    const int w = rem2 >> 6, lane = rem2 & 63;
    const int r = mt * 16 + (lane & 15);
    const int d = w * 32 + (lane >> 4) * 8;
    u16 o[8];
    if (r < 36) {
      const float* p = img + (((size_t)(i * 36 + r)) << 10) + d;
      const float4 v0 = *(const float4*)p;
      const float4 v1 = *(const float4*)(p + 4);
      o[0] = f2bf(v0.x); o[1] = f2bf(v0.y); o[2] = f2bf(v0.z); o[3] = f2bf(v0.w);
      o[4] = f2bf(v1.x); o[5] = f2bf(v1.y); o[6] = f2bf(v1.z); o[7] = f2bf(v1.w);
    } else {
#pragma unroll
      for (int e = 0; e < 8; ++e) o[e] = 0;
    }
    *(uint4*)(imgF + (size_t)g * 8) = *(const uint4*)o;
  }
}

// ---------------------------------------------------------------------------
// Merged GEMM launch: [0,640) s1gemm; [640,944) gemmw; [944,976) gram.
// gemmw img part -> cwF fragment layout; cap part -> preP fragment layout.
__global__ __launch_bounds__(256, 2) void gemms_k(
    const u16* __restrict__ capb, const u16* __restrict__ imgb,
    const u16* __restrict__ WTl, const u16* __restrict__ WTg,
    u16* __restrict__ prePL, u16* __restrict__ prePG,
    u16* __restrict__ cwFL, u16* __restrict__ cwFG,
    const float* __restrict__ bL, const float* __restrict__ bG,
    float* __restrict__ S1, u16* __restrict__ Ghi, u16* __restrict__ Glo) {
  __shared__ __align__(16) char lsU[20480];
  const int bid = blockIdx.x;
  const int tid = threadIdx.x;
  const int wv = tid >> 6, lane = tid & 63;
  const int quad = lane >> 4, l15 = lane & 15;
  const bf16x8 zero8 = {0, 0, 0, 0, 0, 0, 0, 0};

  if (bid < 640) {
    // ---- S1 GEMM: out[i][m][r] = sum_d cap[m,d]*ctx_i[r,d]; m-tile 64.
    u16* lsA = (u16*)lsU;
    u16* lsB = (u16*)(lsU + 4096);
    const int i = bid & 31, m0 = (bid >> 5) * 64;
    const u16* B = imgb + (size_t)i * 36 * 1024;
    f32x4 acc[3];
#pragma unroll
    for (int b = 0; b < 3; ++b) acc[b] = (f32x4){0.f, 0.f, 0.f, 0.f};
    for (int kt = 0; kt < 32; ++kt) {
      if (kt) __syncthreads();
      const int rr = tid >> 2, j = tid & 3;
      const int js = j ^ ((rr >> 2) & 3);
      gl2lds16(capb + (size_t)(m0 + rr) * 1024 + kt * 32 + js * 8,
               lsA + (size_t)(wv * 64) * 8);
      const int rc = rr < 36 ? rr : 35;
      gl2lds16(B + (size_t)rc * 1024 + kt * 32 + js * 8,
               lsB + (size_t)(wv * 64) * 8);
      __syncthreads();
      const int ra = wv * 16 + l15;
      const bf16x8 a2 = *(const bf16x8*)(lsA + ra * 32 + (quad ^ ((ra >> 2) & 3)) * 8);
      bf16x8 b3[3];
#pragma unroll
      for (int nf = 0; nf < 3; ++nf) {
        const int rb = nf * 16 + l15;
        const bf16x8 bv = *(const bf16x8*)(lsB + rb * 32 + (quad ^ ((rb >> 2) & 3)) * 8);
        b3[nf] = (rb < 36) ? bv : zero8;
      }
#pragma unroll
      for (int nf = 0; nf < 3; ++nf) acc[nf] = MFMA_BF16(a2, b3[nf], acc[nf]);
    }
#pragma unroll
    for (int nf = 0; nf < 3; ++nf)
#pragma unroll
      for (int rg = 0; rg < 4; ++rg) {
        const int m = m0 + wv * 16 + quad * 4 + rg;
        S1[((size_t)i * 1280 + m) * 48 + nf * 16 + l15] = acc[nf][rg];
      }
  } else if (bid < 944) {
    // ---- dual-B GEMM over A = [capb(1280); imgb(1152)], K=1024.
    u16* lsA = (u16*)lsU;
    u16* lsBl = (u16*)(lsU + 4096);
    u16* lsBg = (u16*)(lsU + 12288);
    const int b2 = bid - 640;
    const int bm = b2 >> 3, bn = b2 & 7;
    const bool iscap = bm < 20;
    const u16* A = iscap ? capb + (size_t)bm * 64 * 1024
                         : imgb + (size_t)(bm - 20) * 64 * 1024;
    const int kofs = iscap ? 0 : 1024;
    const int wm = (wv & 1) * 32, wn = (wv >> 1) * 64;
    f32x4 accL[2][4], accG[2][4];
#pragma unroll
    for (int a = 0; a < 2; ++a)
#pragma unroll
      for (int b = 0; b < 4; ++b) {
        accL[a][b] = (f32x4){0.f, 0.f, 0.f, 0.f};
        accG[a][b] = (f32x4){0.f, 0.f, 0.f, 0.f};
      }
    for (int kt = 0; kt < 32; ++kt) {
      if (kt) __syncthreads();
      {
        const int row = tid >> 2, c8 = tid & 3;
        const int js = c8 ^ (row & 3);
        gl2lds16(A + (size_t)row * 1024 + kt * 32 + js * 8,
                 lsA + (size_t)(wv * 64) * 8);
      }
#pragma unroll
      for (int s = 0; s < 2; ++s) {
        const int idx = s * 256 + tid;
        const int row = idx >> 2, c8 = idx & 3;
        const int js = c8 ^ (row & 3);
        const size_t bro = (size_t)(bn * 128 + row) * 2048 + kofs + kt * 32 + js * 8;
        gl2lds16(WTl + bro, lsBl + (size_t)(s * 256 + wv * 64) * 8);
        gl2lds16(WTg + bro, lsBg + (size_t)(s * 256 + wv * 64) * 8);
      }
      __syncthreads();
      bf16x8 af[2], bl8[4], bg8[4];
#pragma unroll
      for (int mt = 0; mt < 2; ++mt) {
        const int ra = wm + mt * 16 + l15;
        af[mt] = *(const bf16x8*)(lsA + ra * 32 + (quad ^ (ra & 3)) * 8);
      }
#pragma unroll
      for (int nt = 0; nt < 4; ++nt) {
        const int rb = wn + nt * 16 + l15;
        const int off = rb * 32 + (quad ^ (rb & 3)) * 8;
        bl8[nt] = *(const bf16x8*)(lsBl + off);
        bg8[nt] = *(const bf16x8*)(lsBg + off);
      }
#pragma unroll
      for (int mt = 0; mt < 2; ++mt)
#pragma unroll
        for (int nt = 0; nt < 4; ++nt) {
          accL[mt][nt] = MFMA_BF16(af[mt], bl8[nt], accL[mt][nt]);
          accG[mt][nt] = MFMA_BF16(af[mt], bg8[nt], accG[mt][nt]);
        }
    }
#pragma unroll
    for (int mt = 0; mt < 2; ++mt)
#pragma unroll
      for (int nt = 0; nt < 4; ++nt) {
        const int n = bn * 128 + wn + nt * 16 + l15;
        if (iscap) {
          const float blv = bL[n], bgv = bG[n];
#pragma unroll
          for (int r = 0; r < 4; ++r) {
            const int m = bm * 64 + wm + mt * 16 + quad * 4 + r;
            const size_t fi = fragIdx(m, n);
            prePL[fi] = f2bf(accL[mt][nt][r] + blv);
            prePG[fi] = f2bf(accG[mt][nt][r] + bgv);
          }
        } else {
          const int db = n >> 4, l15d = n & 15;
#pragma unroll
          for (int r = 0; r < 4; ++r) {
            const int mi = (bm - 20) * 64 + wm + mt * 16 + quad * 4 + r;
            const int i = (mi * 3641) >> 17;   // floor(mi/36), mi<1152
            const int r36 = mi - i * 36;
            const int ksr = r36 >> 5, qd = (r36 & 31) >> 3, e = r36 & 7;
            const size_t gb =
                ((((size_t)i * 64 + db) * 2 + ksr) * 64 + qd * 16 + l15d) * 8 + e;
            cwFL[gb] = f2bf(accL[mt][nt][r]);
            cwFG[gb] = f2bf(accG[mt][nt][r]);
          }
        }
      }
  } else {
    // ---- per-image Gram: G[i] = ctx_i @ ctx_i^T, [48][64] bf16 hi+lo.
    float* lsS = (float*)lsU;  // 48*52*4 = 9984B
    const int i = bid - 944;
    for (int k = tid; k < 48 * 52; k += 256) lsS[k] = 0.f;
    const u16* arow[3]; bool avalid[3];
#pragma unroll
    for (int mt = 0; mt < 3; ++mt) {
      const int r = mt * 16 + l15;
      avalid[mt] = r < 36;
      arow[mt] = imgb + ((size_t)(i * 36 + (r < 36 ? r : 35)) << 10);
    }
    f32x4 acc[3][3];
#pragma unroll
    for (int a = 0; a < 3; ++a)
#pragma unroll
      for (int b = 0; b < 3; ++b) acc[a][b] = (f32x4){0.f, 0.f, 0.f, 0.f};
    for (int kk = wv * 8; kk < wv * 8 + 8; ++kk) {
      const int ko = kk * 32 + quad * 8;
      bf16x8 af[3];
#pragma unroll
      for (int mt = 0; mt < 3; ++mt)
        af[mt] = avalid[mt] ? *(const bf16x8*)(arow[mt] + ko) : zero8;
#pragma unroll
      for (int mt = 0; mt < 3; ++mt)
#pragma unroll
        for (int nt = 0; nt < 3; ++nt)
          acc[mt][nt] = MFMA_BF16(af[mt], af[nt], acc[mt][nt]);
    }
    __syncthreads();
#pragma unroll
    for (int mt = 0; mt < 3; ++mt)
#pragma unroll
      for (int nt = 0; nt < 3; ++nt)
#pragma unroll
        for (int rg = 0; rg < 4; ++rg)
          atomicAdd(&lsS[(nt * 16 + l15) * 52 + mt * 16 + quad * 4 + rg],
                    acc[mt][nt][rg]);
    __syncthreads();
    if (wv == 0) {
#pragma unroll
      for (int nt = 0; nt < 3; ++nt) {
        const int rp = nt * 16 + l15;
#pragma unroll
        for (int mt = 0; mt < 3; ++mt) {
          const f32x4 g = *(const f32x4*)&lsS[rp * 52 + mt * 16 + quad * 4];
          u16 hv[4], lv[4];
#pragma unroll
          for (int rg = 0; rg < 4; ++rg) {
            hv[rg] = f2bf(g[rg]);
            lv[rg] = f2bf(g[rg] - bf2f(hv[rg]));
          }
          const size_t gb = ((size_t)i * 48 + rp) * 64 + mt * 16 + quad * 4;
          *(uint2*)(Ghi + gb) = *(const uint2*)hv;
          *(uint2*)(Glo + gb) = *(const uint2*)lv;
        }
      }
    }
    for (int k = tid; k < 48 * 16; k += 256) {  // zero cols 48..63
      const size_t gb = ((size_t)i * 48 + (k >> 4)) * 64 + 48 + (k & 15);
      Ghi[gb] = 0; Glo[gb] = 0;
    }
  }
}

// ---------------------------------------------------------------------------
// Fused gate + S2, fully de-staged (R21 structure, grid 1280, 8 chunks).
// All global accesses wave-contiguous (cwF/imgF 1KB, preP/capP 512B per
// instruction). NO in-loop barriers; LDS = S2 merge only (6.7KB).
__global__ __launch_bounds__(256, 4) void gates2_k(
    const u16* __restrict__ cwFL, const u16* __restrict__ cwFG,
    const u16* __restrict__ P1, const u16* __restrict__ prePL,
    const u16* __restrict__ prePG, const u16* __restrict__ capP,
    const u16* __restrict__ imgF, float* __restrict__ S2) {
  __shared__ __align__(16) float lsS2f[32 * 52];
  const int tid = threadIdx.x;
  const int bid = blockIdx.x;
  const int i = bid & 31, ctt = bid >> 5;  // i fastest: image i -> XCD i%8
  const int ct0 = ctt * 32;
  const int wv = tid >> 6, lane = tid & 63;
  const int quad = lane >> 4, l15 = lane & 15;

  for (int k = tid; k < 32 * 52; k += 256) lsS2f[k] = 0.f;
  __syncthreads();

  // hoisted P1 B-frags (loop-invariant; r>=36 exact zero from score_k)
  bf16x8 bp[2][2];
#pragma unroll
  for (int nt = 0; nt < 2; ++nt)
#pragma unroll
    for (int ks = 0; ks < 2; ++ks)
      bp[nt][ks] = *(const bf16x8*)(
          P1 + ((size_t)i * 1280 + ct0 + nt * 16 + l15) * 64 + ks * 32 + quad * 8);

  f32x4 acc2[3][2];
#pragma unroll
  for (int a = 0; a < 3; ++a)
#pragma unroll
    for (int b = 0; b < 2; ++b) acc2[a][b] = (f32x4){0.f, 0.f, 0.f, 0.f};

  for (int dc = 0; dc < 8; ++dc) {
    // ---- gate GEMM: cwF frags in-chunk (1KB contiguous per wave)
    f32x4 accL[2][2], accG[2][2];
#pragma unroll
    for (int a = 0; a < 2; ++a)
#pragma unroll
      for (int b = 0; b < 2; ++b) {
        accL[a][b] = (f32x4){0.f, 0.f, 0.f, 0.f};
        accG[a][b] = (f32x4){0.f, 0.f, 0.f, 0.f};
      }
#pragma unroll
    for (int mt = 0; mt < 2; ++mt)
#pragma unroll
      for (int ks = 0; ks < 2; ++ks) {
        const int db = dc * 8 + wv * 2 + mt;
        const size_t co = ((((size_t)i * 64 + db) * 2 + ks) * 64 + lane) * 8;
        const bf16x8 al = *(const bf16x8*)(cwFL + co);
        const bf16x8 ag = *(const bf16x8*)(cwFG + co);
#pragma unroll
        for (int nt = 0; nt < 2; ++nt) {
          accL[mt][nt] = MFMA_BF16(al, bp[nt][ks], accL[mt][nt]);
          accG[mt][nt] = MFMA_BF16(ag, bp[nt][ks], accG[mt][nt]);
        }
      }

    // ---- gating epilogue: fragment-layout global loads (512B/instr)
    const size_t fb = (((size_t)ctt * 8 + dc) * 4 + wv) * 2;
    uint2 ovv[2][2];
#pragma unroll
    for (int mt = 0; mt < 2; ++mt) {
#pragma unroll
      for (int nt = 0; nt < 2; ++nt) {
        const size_t fo = (((fb + mt) * 2 + nt) * 64 + lane) * 4;
        const uint2 plv = *(const uint2*)(prePL + fo);
        const uint2 pgv = *(const uint2*)(prePG + fo);
        const uint2 cfv = *(const uint2*)(capP + fo);
        const float pl4[4] = {bf2f((u16)(plv.x & 0xffffu)), bf2f((u16)(plv.x >> 16)),
                              bf2f((u16)(plv.y & 0xffffu)), bf2f((u16)(plv.y >> 16))};
        const float pg4[4] = {bf2f((u16)(pgv.x & 0xffffu)), bf2f((u16)(pgv.x >> 16)),
                              bf2f((u16)(pgv.y & 0xffffu)), bf2f((u16)(pgv.y >> 16))};
        const float cf4[4] = {bf2f((u16)(cfv.x & 0xffffu)), bf2f((u16)(cfv.x >> 16)),
                              bf2f((u16)(cfv.y & 0xffffu)), bf2f((u16)(cfv.y >> 16))};
        u16 ov[4];
#pragma unroll
        for (int rg = 0; rg < 4; ++rg) {
          const float aL = accL[mt][nt][rg] + pl4[rg];
          const float aG = accG[mt][nt][rg] + pg4[rg];
          const float g = frcp(1.f + __expf(-aG));
          const float u = 2.f * frcp(1.f + __expf(-2.f * aL)) - 1.f;  // tanh
          ov[rg] = f2bf(cf4[rg] * g + u * (1.f - g));
        }
        ovv[mt][nt] = *(const uint2*)ov;
      }
    }

    // ---- S2 partial: B-frag via quad-permute shuffles; A from imgF pack
#pragma unroll
    for (int nt = 0; nt < 2; ++nt) {
      unsigned w[4];
#pragma unroll
      for (int j2 = 0; j2 < 4; ++j2) {
        const int srcl = ((quad & 1) * 2 + (j2 >> 1)) * 16 + l15;
        const unsigned a0 =
            __shfl((j2 & 1) ? ovv[0][nt].y : ovv[0][nt].x, srcl, 64);
        const unsigned a1 =
            __shfl((j2 & 1) ? ovv[1][nt].y : ovv[1][nt].x, srcl, 64);
        w[j2] = (quad >= 2) ? a1 : a0;
      }
      union { unsigned u[4]; bf16x8 v; } bq;
      bq.u[0] = w[0]; bq.u[1] = w[1]; bq.u[2] = w[2]; bq.u[3] = w[3];
      const int wn = dc * 4 + wv;  // 32-d window index
#pragma unroll
      for (int mt = 0; mt < 3; ++mt) {
        const bf16x8 af = *(const bf16x8*)(
            imgF + ((((size_t)i * 3 + mt) * 32 + wn) * 64 + lane) * 8);
        acc2[mt][nt] = MFMA_BF16(af, bq.v, acc2[mt][nt]);
      }
    }
  }
  // ---- merge wave partials (d-slices), write S2 tile
#pragma unroll
  for (int mt = 0; mt < 3; ++mt)
#pragma unroll
    for (int nt = 0; nt < 2; ++nt)
#pragma unroll
      for (int rg = 0; rg < 4; ++rg)
        atomicAdd(&lsS2f[(nt * 16 + l15) * 52 + mt * 16 + quad * 4 + rg],
                  acc2[mt][nt][rg]);
  __syncthreads();
  for (int idx = tid; idx < 384; idx += 256) {
    const int ct = idx / 12, rq = idx % 12;
    *(f32x4*)(S2 + ((size_t)i * 1280 + ct0 + ct) * 48 + rq * 4) =
        *(const f32x4*)&lsS2f[ct * 52 + rq * 4];
  }
}

// ---------------------------------------------------------------------------
// Per-pair scoring (4 pairs/block, one per wave). Softmax(Ssm) -> P;
// pn = sum P*S1; pw = P^T G P; sim = mean cosine. PASS2=0 also writes P1+sim1;
// PASS2=1 writes score = sim1 + sim2.
template <int PASS2>
__global__ __launch_bounds__(256, 2) void score_k(
    const float* __restrict__ Ssm, const float* __restrict__ S1,
    const u16* __restrict__ Ghi, const u16* __restrict__ Glo,
    const float* __restrict__ cnorm, u16* __restrict__ P1,
    float* __restrict__ sim1, float* __restrict__ score) {
  __shared__ __align__(16) u16 lsP[4][48 * 72];
  const int tid = threadIdx.x;
  const int wv = tid >> 6, lane = tid & 63;
  const int quad = lane >> 4, l15 = lane & 15;
  const int pair = blockIdx.x * 4 + wv;
  const int c = pair >> 5, i = pair & 31;
  u16* lsPw = lsP[wv];
  for (int k = lane; k < 1728; k += 64) ((unsigned*)lsPw)[k] = 0u;

  float sS[3][3][4], s1f[3][3][4];
  const float* Sb = Ssm + ((size_t)i * 1280 + c * 40) * 48;
  const float* S1b = S1 + ((size_t)i * 1280 + c * 40) * 48;
#pragma unroll
  for (int nt = 0; nt < 3; ++nt) {
    const int t = nt * 16 + l15;
    const int tr = t < 40 ? t : 39;
#pragma unroll
    for (int mt = 0; mt < 3; ++mt) {
      f32x4 v = *(const f32x4*)(Sb + (size_t)tr * 48 + mt * 16 + quad * 4);
      if (t >= 40) v = (f32x4){0.f, 0.f, 0.f, 0.f};  // keep l2norm-over-t exact
#pragma unroll
      for (int rg = 0; rg < 4; ++rg) sS[mt][nt][rg] = v[rg];
      if (PASS2) {
        const f32x4 w = *(const f32x4*)(S1b + (size_t)tr * 48 + mt * 16 + quad * 4);
#pragma unroll
        for (int rg = 0; rg < 4; ++rg) s1f[mt][nt][rg] = w[rg];
      } else {
#pragma unroll
        for (int rg = 0; rg < 4; ++rg) s1f[mt][nt][rg] = v[rg];
      }
    }
  }

  // ---- leaky + l2norm over t, temperature softmax over r (in-register)
  float rn[3][4];
#pragma unroll
  for (int mt = 0; mt < 3; ++mt)
#pragma unroll
    for (int rg = 0; rg < 4; ++rg) {
      float s2 = 0.f;
#pragma unroll
      for (int nt = 0; nt < 3; ++nt) {
        float v = sS[mt][nt][rg]; v = v > 0.f ? v : 0.1f * v; s2 += v * v;
      }
      s2 += __shfl_xor(s2, 1, 64); s2 += __shfl_xor(s2, 2, 64);
      s2 += __shfl_xor(s2, 4, 64); s2 += __shfl_xor(s2, 8, 64);
      rn[mt][rg] = sqrtf(s2) + 1e-8f;
    }
  float mx[3] = {-3.0e38f, -3.0e38f, -3.0e38f};
#pragma unroll
  for (int mt = 0; mt < 3; ++mt)
#pragma unroll
    for (int nt = 0; nt < 3; ++nt)
#pragma unroll
      for (int rg = 0; rg < 4; ++rg) {
        const int r = mt * 16 + quad * 4 + rg;
        float v = sS[mt][nt][rg]; v = v > 0.f ? v : 0.1f * v;
        float zz = 9.f * v / rn[mt][rg];
        zz = (r < 36) ? zz : -3.0e38f;
        sS[mt][nt][rg] = zz;
        mx[nt] = fmaxf(mx[nt], zz);
      }
#pragma unroll
  for (int nt = 0; nt < 3; ++nt) {
    mx[nt] = fmaxf(mx[nt], __shfl_xor(mx[nt], 16, 64));
    mx[nt] = fmaxf(mx[nt], __shfl_xor(mx[nt], 32, 64));
  }
  float ss[3] = {0.f, 0.f, 0.f};
#pragma unroll
  for (int mt = 0; mt < 3; ++mt)
#pragma unroll
    for (int nt = 0; nt < 3; ++nt)
#pragma unroll
      for (int rg = 0; rg < 4; ++rg) {
        const float e = __expf(sS[mt][nt][rg] - mx[nt]);
        sS[mt][nt][rg] = e; ss[nt] += e;
      }
#pragma unroll
  for (int nt = 0; nt < 3; ++nt) {
    ss[nt] += __shfl_xor(ss[nt], 16, 64);
    ss[nt] += __shfl_xor(ss[nt], 32, 64);
    ss[nt] = 1.f / ss[nt];
  }
#pragma unroll
  for (int nt = 0; nt < 3; ++nt) {
    const int t = nt * 16 + l15;
#pragma unroll
    for (int mt = 0; mt < 3; ++mt) {
#pragma unroll
      for (int rg = 0; rg < 4; ++rg) sS[mt][nt][rg] *= ss[nt];
      if (t < 40) {
        u16 pv[4];
#pragma unroll
        for (int rg = 0; rg < 4; ++rg) pv[rg] = f2bf(sS[mt][nt][rg]);
        *(uint2*)(lsPw + t * 72 + mt * 16 + quad * 4) = *(const uint2*)pv;
      }
    }
  }

  // ---- pn = sum_r P * S1raw (per t)
  float pnv[3] = {0.f, 0.f, 0.f};
#pragma unroll
  for (int nt = 0; nt < 3; ++nt)
#pragma unroll
    for (int mt = 0; mt < 3; ++mt)
#pragma unroll
      for (int rg = 0; rg < 4; ++rg) pnv[nt] += sS[mt][nt][rg] * s1f[mt][nt][rg];

  // ---- P1 global write (GEMM operand layout, stride 64, zeros beyond r=36)
  if (!PASS2) {
    for (int idx = lane; idx < 320; idx += 64) {
      const int t = idx >> 3, j = idx & 7;
      *(uint4*)(P1 + ((size_t)i * 1280 + c * 40 + t) * 64 + j * 8) =
          *(const uint4*)(lsPw + t * 72 + j * 8);
    }
  }

  // ---- pw = P^T G P via Gram MFMA
  bf16x8 afA[3][2];
#pragma unroll
  for (int mtT = 0; mtT < 3; ++mtT)
#pragma unroll
    for (int ks = 0; ks < 2; ++ks)
      afA[mtT][ks] =
          *(const bf16x8*)(lsPw + (mtT * 16 + l15) * 72 + ks * 32 + quad * 8);
  f32x4 gp[3][3];
#pragma unroll
  for (int a = 0; a < 3; ++a)
#pragma unroll
    for (int b = 0; b < 3; ++b) gp[a][b] = (f32x4){0.f, 0.f, 0.f, 0.f};
#pragma unroll
  for (int ks = 0; ks < 2; ++ks)
#pragma unroll
    for (int mtG = 0; mtG < 3; ++mtG) {
      const size_t gb = ((size_t)i * 48 + mtG * 16 + l15) * 64 + ks * 32 + quad * 8;
      const bf16x8 gh = *(const bf16x8*)(Ghi + gb);
      const bf16x8 gl = *(const bf16x8*)(Glo + gb);
#pragma unroll
      for (int mtT = 0; mtT < 3; ++mtT) {
        gp[mtG][mtT] = MFMA_BF16(gh, afA[mtT][ks], gp[mtG][mtT]);
        gp[mtG][mtT] = MFMA_BF16(gl, afA[mtT][ks], gp[mtG][mtT]);
      }
    }
  float pwv[3] = {0.f, 0.f, 0.f};
#pragma unroll
  for (int nt = 0; nt < 3; ++nt)
#pragma unroll
    for (int mt = 0; mt < 3; ++mt)
#pragma unroll
      for (int rg = 0; rg < 4; ++rg)
        pwv[nt] += sS[mt][nt][rg] * gp[mt][nt][rg];
#pragma unroll
  for (int nt = 0; nt < 3; ++nt) {
    pnv[nt] += __shfl_xor(pnv[nt], 16, 64); pnv[nt] += __shfl_xor(pnv[nt], 32, 64);
    pwv[nt] += __shfl_xor(pwv[nt], 16, 64); pwv[nt] += __shfl_xor(pwv[nt], 32, 64);
  }
  float tot = 0.f;
#pragma unroll
  for (int nt = 0; nt < 3; ++nt) {
    const int t = nt * 16 + l15;
    if (t < 40) {
      const float w2 = sqrtf(fmaxf(pwv[nt], 0.f));
      tot += pnv[nt] / fmaxf(cnorm[c * 40 + t] * w2, 1e-8f);
    }
  }
  tot += __shfl_xor(tot, 1, 64); tot += __shfl_xor(tot, 2, 64);
  tot += __shfl_xor(tot, 4, 64); tot += __shfl_xor(tot, 8, 64);
  if (lane == 0) {
    const float s = tot * (1.f / 40.f);
    if (PASS2) score[i * 32 + c] = sim1[pair] + s;
    else sim1[pair] = s;
  }
}

// ---------------------------------------------------------------------------
extern "C" void kernel_launch(void* const* d_in, const int* in_sizes, int n_in,
                              void* d_out, int out_size, void* d_ws, size_t ws_size,
                              hipStream_t stream) {
  const float* img = (const float*)d_in[0];   // [32][36][1024] fp32
  const float* cap = (const float*)d_in[1];   // [32][40][1024] fp32
  const float* Wl  = (const float*)d_in[2];   // [2048][1024] fp32
  const float* bl  = (const float*)d_in[3];   // [1024] fp32
  const float* Wg  = (const float*)d_in[4];
  const float* bg  = (const float*)d_in[5];
  float* out = (float*)d_out;                 // [32][32] fp32

  char* ws = (char*)d_ws;
  float* cnrm = (float*)ws;               ws += 5120;
  float* sim1 = (float*)ws;               ws += 4096;
  u16*   WTl  = (u16*)ws;                 ws += (size_t)1024 * 2048 * 2;   // 4.2 MB
  u16*   WTg  = (u16*)ws;                 ws += (size_t)1024 * 2048 * 2;   // 4.2 MB
  u16*   prePL= (u16*)ws;                 ws += (size_t)1280 * 1024 * 2;   // 2.6 MB
  u16*   prePG= (u16*)ws;                 ws += (size_t)1280 * 1024 * 2;   // 2.6 MB
  u16*   capb = (u16*)ws;                 ws += (size_t)1280 * 1024 * 2;   // 2.6 MB
  u16*   capP = (u16*)ws;                 ws += (size_t)1280 * 1024 * 2;   // 2.6 MB
  u16*   imgb = (u16*)ws;                 ws += (size_t)1152 * 1024 * 2;   // 2.4 MB
  u16*   imgF = (u16*)ws;                 ws += (size_t)32 * 3 * 32 * 64 * 8 * 2;  // 3.1 MB
  u16*   Ghi  = (u16*)ws;                 ws += (size_t)32 * 48 * 64 * 2;  // 196 KB
  u16*   Glo  = (u16*)ws;                 ws += (size_t)32 * 48 * 64 * 2;  // 196 KB
  u16*   cwFL = (u16*)ws;                 ws += (size_t)32 * 64 * 2 * 64 * 8 * 2;  // 4.2 MB
  u16*   cwFG = (u16*)ws;                 ws += (size_t)32 * 64 * 2 * 64 * 8 * 2;  // 4.2 MB
  float* S1   = (float*)ws;               ws += (size_t)32 * 1280 * 48 * 4;  // 7.9 MB
  float* S2   = (float*)ws;               ws += (size_t)32 * 1280 * 48 * 4;  // 7.9 MB
  u16*   P1   = (u16*)ws;                 ws += (size_t)32 * 1280 * 64 * 2;  // 5.2 MB

  prep_k<<<9664, 256, 0, stream>>>(img, cap, Wl, Wg, imgb, capb, capP, imgF,
                                   WTl, WTg, cnrm, cwFL);
  gemms_k<<<976, 256, 0, stream>>>(capb, imgb, WTl, WTg, prePL, prePG,
                                   cwFL, cwFG, bl, bg, S1, Ghi, Glo);
  score_k<0><<<256, 256, 0, stream>>>(S1, S1, Ghi, Glo, cnrm, P1, sim1, out);
  gates2_k<<<1280, 256, 0, stream>>>(cwFL, cwFG, P1, prePL, prePG, capP,
                                     imgF, S2);
  score_k<1><<<256, 256, 0, stream>>>(S2, S1, Ghi, Glo, cnrm, P1, sim1, out);
}